// Round 4
// baseline (248.433 us; speedup 1.0000x reference)
//
#include <hip/hip_runtime.h>
#include <math.h>

#define NSTATE 64
#define LEN    4096
#define NH     256
#define NB     16

// Ksym natural order (freq output); rev16-digit-reversed + (1/4096)-scaled (fftconv input)
__device__ float2 g_knat[NH * LEN];
__device__ float2 g_ksym[NH * LEN];
// per-(h,n) Cauchy params: A={lam_r,lam_i,|P|^2,pad} B={v0r,v0i,v1r,v1i} C={v2r,v2i}
__device__ float4 g_pA[NH * NSTATE];
__device__ float4 g_pB[NH * NSTATE];
__device__ float2 g_pC[NH * NSTATE];

// ---------------- complex helpers ----------------
__device__ __forceinline__ float2 cadd(float2 a, float2 b){ return make_float2(a.x+b.x, a.y+b.y); }
__device__ __forceinline__ float2 csub(float2 a, float2 b){ return make_float2(a.x-b.x, a.y-b.y); }
__device__ __forceinline__ float2 cmul(float2 a, float2 b){ return make_float2(a.x*b.x - a.y*b.y, a.x*b.y + a.y*b.x); }
__device__ __forceinline__ float2 mulnegi(float2 a){ return make_float2(a.y, -a.x); }
__device__ __forceinline__ float2 mulposi(float2 a){ return make_float2(-a.y, a.x); }

#define RSQ2 0.70710678118654752f
#define C16  0.92387953251128675613f   // cos(pi/8)
#define S16  0.38268343236508977173f   // sin(pi/8)

// 16-point DFT (W16 = e^{-2pi i/16}), natural-order in and out. 4x4 Cooley-Tukey.
__device__ __forceinline__ void bfly16_fwd(float2 v[16]) {
#pragma unroll
  for (int n1 = 0; n1 < 4; ++n1) {       // pass 1: DFT4 over stride-4 columns
    float2 a=v[n1], b=v[n1+4], c=v[n1+8], d=v[n1+12];
    float2 t0=cadd(a,c), t1=csub(a,c), t2=cadd(b,d), t3=csub(b,d);
    v[n1]    = cadd(t0,t2);
    v[n1+4]  = cadd(t1, mulnegi(t3));
    v[n1+8]  = csub(t0,t2);
    v[n1+12] = cadd(t1, mulposi(t3));
  }
  // twiddle W16^{n1*k2} on slot v[n1 + 4*k2]
  v[5]  = cmul(v[5],  make_float2(C16,-S16));                                // W1
  v[9]  = make_float2(RSQ2*(v[9].x + v[9].y),  RSQ2*(v[9].y - v[9].x));      // W2
  v[13] = cmul(v[13], make_float2(S16,-C16));                                // W3
  v[6]  = make_float2(RSQ2*(v[6].x + v[6].y),  RSQ2*(v[6].y - v[6].x));      // W2
  v[10] = mulnegi(v[10]);                                                    // W4
  v[14] = make_float2(RSQ2*(v[14].y - v[14].x), -RSQ2*(v[14].x + v[14].y));  // W6
  v[7]  = cmul(v[7],  make_float2(S16,-C16));                                // W3
  v[11] = make_float2(RSQ2*(v[11].y - v[11].x), -RSQ2*(v[11].x + v[11].y));  // W6
  v[15] = cmul(v[15], make_float2(-C16,S16));                                // W9
  float2 r[16];
#pragma unroll
  for (int k2 = 0; k2 < 4; ++k2) {       // pass 2: DFT4 over contiguous rows -> natural order
    float2 a=v[4*k2], b=v[4*k2+1], c=v[4*k2+2], d=v[4*k2+3];
    float2 t0=cadd(a,c), t1=csub(a,c), t2=cadd(b,d), t3=csub(b,d);
    r[k2]    = cadd(t0,t2);
    r[k2+4]  = cadd(t1, mulnegi(t3));
    r[k2+8]  = csub(t0,t2);
    r[k2+12] = cadd(t1, mulposi(t3));
  }
#pragma unroll
  for (int i = 0; i < 16; ++i) v[i] = r[i];
}

// conjugate-kernel (unscaled inverse) 16-point DFT
__device__ __forceinline__ void bfly16_inv(float2 v[16]) {
#pragma unroll
  for (int n1 = 0; n1 < 4; ++n1) {
    float2 a=v[n1], b=v[n1+4], c=v[n1+8], d=v[n1+12];
    float2 t0=cadd(a,c), t1=csub(a,c), t2=cadd(b,d), t3=csub(b,d);
    v[n1]    = cadd(t0,t2);
    v[n1+4]  = cadd(t1, mulposi(t3));
    v[n1+8]  = csub(t0,t2);
    v[n1+12] = cadd(t1, mulnegi(t3));
  }
  v[5]  = cmul(v[5],  make_float2(C16,S16));
  v[9]  = make_float2(RSQ2*(v[9].x - v[9].y),  RSQ2*(v[9].x + v[9].y));      // conj W2
  v[13] = cmul(v[13], make_float2(S16,C16));
  v[6]  = make_float2(RSQ2*(v[6].x - v[6].y),  RSQ2*(v[6].x + v[6].y));
  v[10] = mulposi(v[10]);
  v[14] = make_float2(-RSQ2*(v[14].x + v[14].y), RSQ2*(v[14].x - v[14].y));  // conj W6
  v[7]  = cmul(v[7],  make_float2(S16,C16));
  v[11] = make_float2(-RSQ2*(v[11].x + v[11].y), RSQ2*(v[11].x - v[11].y));
  v[15] = cmul(v[15], make_float2(-C16,-S16));
  float2 r[16];
#pragma unroll
  for (int k2 = 0; k2 < 4; ++k2) {
    float2 a=v[4*k2], b=v[4*k2+1], c=v[4*k2+2], d=v[4*k2+3];
    float2 t0=cadd(a,c), t1=csub(a,c), t2=cadd(b,d), t3=csub(b,d);
    r[k2]    = cadd(t0,t2);
    r[k2+4]  = cadd(t1, mulposi(t3));
    r[k2+8]  = csub(t0,t2);
    r[k2+12] = cadd(t1, mulnegi(t3));
  }
#pragma unroll
  for (int i = 0; i < 16; ++i) v[i] = r[i];
}

// v[m] *= w^m, m=1..15
__device__ __forceinline__ void twiddle15(float2 v[16], float wr, float wi) {
  float2 w = make_float2(wr, wi);
  float2 p = w;
  v[1] = cmul(v[1], p);
#pragma unroll
  for (int m = 2; m < 16; ++m) { p = cmul(p, w); v[m] = cmul(v[m], p); }
}

// ---------------- param precompute ----------------
__global__ __launch_bounds__(256) void s4_prep(
    const float* __restrict__ Lre, const float* __restrict__ Lim,
    const float* __restrict__ Pre, const float* __restrict__ Pim,
    const float* __restrict__ Bre, const float* __restrict__ Bim,
    const float* __restrict__ Cre, const float* __restrict__ Cim)
{
  int idx = blockIdx.x * 256 + threadIdx.x;
  if (idx >= NH * NSTATE) return;
  float lr = Lre[idx], li = Lim[idx];
  float pr = Pre[idx], pi = Pim[idx];
  float br = Bre[idx], bi = Bim[idx];
  float cr = Cre[idx], ci = Cim[idx];
  g_pA[idx] = make_float4(lr, li, pr * pr + pi * pi, 0.0f);
  g_pB[idx] = make_float4(cr * br + ci * bi, cr * bi - ci * br,
                          cr * pr + ci * pi, cr * pi - ci * pr);
  g_pC[idx] = make_float2(pr * br + pi * bi, pr * bi - pi * br);
}

// ---------------- frequency-domain S4 kernel (unchanged from R3) ----------------
__global__ __launch_bounds__(256) void s4_kernel_freq(const float* __restrict__ log_step)
{
  const int b = blockIdx.x;
  const int h = b >> 2;
  const int q = ((b & 3) << 8) | threadIdx.x;  // 0..1023
  const float step = expf(log_step[h]);
  const float ts = 2.0f / step;
  const float NEG2PI = -6.2831853071795864769f;

  float gar, gai, car, cai, gbr, gbi, cbr, cbi;
  float gcr, gci, ccr, cci, gdr, gdi, cdr, cdi;
  {
    float so, co;
    sincosf(NEG2PI * ((float)q * (1.0f / (float)LEN)), &so, &co);
    float dr = 1.0f + co, di = so;
    float inv = 1.0f / fmaf(dr, dr, di * di);
    car = 2.0f * dr * inv; cai = -2.0f * di * inv;
    float nr = 1.0f - co, ni = -so;
    gar = ts * (fmaf(nr, dr, ni * di) * inv);
    gai = ts * (fmaf(ni, dr, -nr * di) * inv);
  }
  if (q == 0) {
    float so, co;
    sincosf(NEG2PI * 0.5f, &so, &co);
    float dr = 1.0f + co, di = so;
    float inv = 1.0f / fmaf(dr, dr, di * di);
    cbr = 2.0f * dr * inv; cbi = -2.0f * di * inv;
    float nr = 1.0f - co, ni = -so;
    gbr = ts * (fmaf(nr, dr, ni * di) * inv);
    gbi = ts * (fmaf(ni, dr, -nr * di) * inv);
  } else {
    gbr = gar; gbi = -gai; cbr = car; cbi = -cai;
  }
  {
    float so, co;
    sincosf(NEG2PI * ((float)(q + 1024) * (1.0f / (float)LEN)), &so, &co);
    float dr = 1.0f + co, di = so;
    float inv = 1.0f / fmaf(dr, dr, di * di);
    ccr = 2.0f * dr * inv; cci = -2.0f * di * inv;
    float nr = 1.0f - co, ni = -so;
    gcr = ts * (fmaf(nr, dr, ni * di) * inv);
    gci = ts * (fmaf(ni, dr, -nr * di) * inv);
  }
  gdr = gcr; gdi = -gci; cdr = ccr; cdi = -cci;

  float A00r=0,A00i=0,A01r=0,A01i=0,A10r=0,A10i=0,A11r=0,A11i=0;
  float B00r=0,B00i=0,B01r=0,B01i=0,B10r=0,B10i=0,B11r=0,B11i=0;
  float C00r=0,C00i=0,C01r=0,C01i=0,C10r=0,C10i=0,C11r=0,C11i=0;
  float D00r=0,D00i=0,D01r=0,D01i=0,D10r=0,D10i=0,D11r=0,D11i=0;

  const float4* __restrict__ pa = g_pA + h * NSTATE;
  const float4* __restrict__ pb = g_pB + h * NSTATE;
  const float2* __restrict__ pc = g_pC + h * NSTATE;

#define CAUCHY(gre, gim, k00r,k00i,k01r,k01i,k10r,k10i,k11r,k11i)            \
  {                                                                          \
    float rd = gre - Av.x, id = gim - Av.y;                                  \
    float idn = __builtin_amdgcn_rcpf(fmaf(rd, rd, id * id));                \
    float ir = rd * idn, ii = -(id * idn);                                   \
    k00r = fmaf(Bv.x, ir, k00r); k00r = fmaf(-Bv.y, ii, k00r);               \
    k00i = fmaf(Bv.x, ii, k00i); k00i = fmaf(Bv.y, ir, k00i);                \
    k01r = fmaf(Bv.z, ir, k01r); k01r = fmaf(-Bv.w, ii, k01r);               \
    k01i = fmaf(Bv.z, ii, k01i); k01i = fmaf(Bv.w, ir, k01i);                \
    k10r = fmaf(Cv.x, ir, k10r); k10r = fmaf(-Cv.y, ii, k10r);               \
    k10i = fmaf(Cv.x, ii, k10i); k10i = fmaf(Cv.y, ir, k10i);                \
    k11r = fmaf(Av.z, ir, k11r); k11i = fmaf(Av.z, ii, k11i);                \
  }

#pragma unroll 4
  for (int n = 0; n < NSTATE; ++n) {
    float4 Av = pa[n];
    float4 Bv = pb[n];
    float2 Cv = pc[n];
    CAUCHY(gar, gai, A00r,A00i,A01r,A01i,A10r,A10i,A11r,A11i)
    CAUCHY(gbr, gbi, B00r,B00i,B01r,B01i,B10r,B10i,B11r,B11i)
    CAUCHY(gcr, gci, C00r,C00i,C01r,C01i,C10r,C10i,C11r,C11i)
    CAUCHY(gdr, gdi, D00r,D00i,D01r,D01i,D10r,D10i,D11r,D11i)
  }
#undef CAUCHY

#define FINISH(cr_, ci_, k00r,k00i,k01r,k01i,k10r,k10i,k11r,k11i, Kr, Ki)    \
  {                                                                          \
    float rr = 1.0f + k11r, ri = k11i;                                       \
    float rinv = 1.0f / fmaf(rr, rr, ri * ri);                               \
    float pr_ = k01r * k10r - k01i * k10i;                                   \
    float pi_ = k01r * k10i + k01i * k10r;                                   \
    float wr = (pr_ * rr + pi_ * ri) * rinv;                                 \
    float wi = (pi_ * rr - pr_ * ri) * rinv;                                 \
    float sr = k00r - wr, si = k00i - wi;                                    \
    Kr = cr_ * sr - ci_ * si; Ki = cr_ * si + ci_ * sr;                      \
  }

  float Kar, Kai, Kbr, Kbi, Kcr, Kci, Kdr, Kdi;
  FINISH(car, cai, A00r,A00i,A01r,A01i,A10r,A10i,A11r,A11i, Kar, Kai)
  FINISH(cbr, cbi, B00r,B00i,B01r,B01i,B10r,B10i,B11r,B11i, Kbr, Kbi)
  FINISH(ccr, cci, C00r,C00i,C01r,C01i,C10r,C10i,C11r,C11i, Kcr, Kci)
  FINISH(cdr, cdi, D00r,D00i,D01r,D01i,D10r,D10i,D11r,D11i, Kdr, Kdi)
#undef FINISH

  float2* out = g_knat + (size_t)h * LEN;
  if (q == 0) {
    out[0]    = make_float2(Kar, 0.0f);
    out[2048] = make_float2(Kbr, 0.0f);
  } else {
    float fr = 0.5f * (Kar + Kbr), fi = 0.5f * (Kai - Kbi);
    out[q]        = make_float2(fr, fi);
    out[LEN - q]  = make_float2(fr, -fi);
  }
  {
    float fr = 0.5f * (Kcr + Kdr), fi = 0.5f * (Kci - Kdi);
    out[1024 + q] = make_float2(fr, fi);
    out[3072 - q] = make_float2(fr, -fi);
  }
}

// ------- reorder natural -> rev16 digit-reversed, fold in 1/4096 ifft scale -------
__global__ __launch_bounds__(256) void s4_reorder()
{
  __shared__ float2 s[LEN];   // swizzle: phys(i) = i ^ ((i>>8)&15)
  const int h = blockIdx.x, t = threadIdx.x;
  const float2* __restrict__ in = g_knat + (size_t)h * LEN;
  float2* __restrict__ out = g_ksym + (size_t)h * LEN;
  for (int i = t; i < LEN; i += 256) s[i ^ ((i >> 8) & 15)] = in[i];
  __syncthreads();
  const float sc = 1.0f / (float)LEN;
  for (int p = t; p < LEN; p += 256) {
    int f = ((p & 15) << 8) | (p & 0xF0) | (p >> 8);   // swap outer base-16 digits
    float2 k = s[f ^ ((f >> 8) & 15)];
    out[p] = make_float2(k.x * sc, k.y * sc);
  }
}

// ------------- FFT convolution: register radix-16, 4096 = 16^3 -------------
// 256 threads x 16 points. In-place stages (each thread owns its 16 slots) ->
// only 4 barriers. LDS swizzle ph(a) = a ^ ((a>>4)&15): conflict-free for
// stride-256, stride-16 and contiguous-16 patterns. 32 KB LDS -> 5 blocks/CU.
#define PH(a) ((a) ^ (((a) >> 4) & 15))

__global__ __launch_bounds__(256, 5) void s4_fftconv(const float* __restrict__ u,
                                                    float* __restrict__ y)
{
  __shared__ float2 X[LEN];

  const int t = threadIdx.x;
  const int bid = blockIdx.x;
  const int h  = bid & (NH - 1);
  const int bp = bid >> 8;          // packs batches (bp, bp+8) as re/im

  float cA, sA, cB, sB;
  sincosf((float)t        * (-6.2831853071795864769f / 4096.0f), &sA, &cA);
  sincosf((float)(t & 15) * (-6.2831853071795864769f /  256.0f), &sB, &cB);

  const float* u1 = u + ((size_t)bp * NH + h) * LEN;
  const float* u2 = u + ((size_t)(bp + 8) * NH + h) * LEN;

  float2 v[16];
  // ---- fwd stage A (sets {j + 256 m}, j = t): global -> regs, coalesced
#pragma unroll
  for (int m = 0; m < 16; ++m)
    v[m] = make_float2(u1[t + 256 * m], u2[t + 256 * m]);
  bfly16_fwd(v);
  twiddle15(v, cA, sA);
#pragma unroll
  for (int m = 0; m < 16; ++m) { int a = t + 256 * m; X[PH(a)] = v[m]; }
  __syncthreads();

  // ---- fwd stage B (sets {Bk*256 + j2 + 16 s}), in-place
  const int baseB = (t >> 4) * 256 + (t & 15);
#pragma unroll
  for (int s = 0; s < 16; ++s) { int a = baseB + 16 * s; v[s] = X[PH(a)]; }
  bfly16_fwd(v);
  twiddle15(v, cB, sB);
#pragma unroll
  for (int n = 0; n < 16; ++n) { int a = baseB + 16 * n; X[PH(a)] = v[n]; }
  __syncthreads();

  // ---- fused middle: fwd stage C + pointwise K (rev16 order, pre-scaled) + inv C'
  {
    const float4* kp = (const float4*)(g_ksym + (size_t)h * LEN + 16 * t);
    float4 kq[8];
#pragma unroll
    for (int i = 0; i < 8; ++i) kq[i] = kp[i];   // issue early, overlap LDS reads
#pragma unroll
    for (int k = 0; k < 16; ++k) { int a = 16 * t + k; v[k] = X[PH(a)]; }
    bfly16_fwd(v);
#pragma unroll
    for (int i = 0; i < 8; ++i) {
      v[2*i]   = cmul(v[2*i],   make_float2(kq[i].x, kq[i].y));
      v[2*i+1] = cmul(v[2*i+1], make_float2(kq[i].z, kq[i].w));
    }
    bfly16_inv(v);
#pragma unroll
    for (int k = 0; k < 16; ++k) { int a = 16 * t + k; X[PH(a)] = v[k]; }
  }
  __syncthreads();

  // ---- inv stage B' : conj twiddle BEFORE inverse butterfly, in-place
#pragma unroll
  for (int n = 0; n < 16; ++n) { int a = baseB + 16 * n; v[n] = X[PH(a)]; }
  twiddle15(v, cB, -sB);
  bfly16_inv(v);
#pragma unroll
  for (int s = 0; s < 16; ++s) { int a = baseB + 16 * s; X[PH(a)] = v[s]; }
  __syncthreads();

  // ---- inv stage A' : output natural order, straight to global
#pragma unroll
  for (int m = 0; m < 16; ++m) { int a = t + 256 * m; v[m] = X[PH(a)]; }
  twiddle15(v, cA, -sA);
  bfly16_inv(v);

  float* y1 = y + ((size_t)bp * NH + h) * LEN;
  float* y2 = y + ((size_t)(bp + 8) * NH + h) * LEN;
#pragma unroll
  for (int s = 0; s < 16; ++s) {
    y1[t + 256 * s] = v[s].x;     // batch bp   = Re (1/4096 folded into K)
    y2[t + 256 * s] = v[s].y;     // batch bp+8 = Im
  }
}

extern "C" void kernel_launch(void* const* d_in, const int* in_sizes, int n_in,
                              void* d_out, int out_size, void* d_ws, size_t ws_size,
                              hipStream_t stream) {
  const float* u    = (const float*)d_in[0];
  const float* Lre  = (const float*)d_in[1];
  const float* Lim  = (const float*)d_in[2];
  const float* Pre  = (const float*)d_in[3];
  const float* Pim  = (const float*)d_in[4];
  const float* Bre  = (const float*)d_in[5];
  const float* Bim  = (const float*)d_in[6];
  const float* Cre  = (const float*)d_in[7];
  const float* Cim  = (const float*)d_in[8];
  const float* lstep = (const float*)d_in[9];
  float* y = (float*)d_out;

  s4_prep<<<(NH * NSTATE + 255) / 256, 256, 0, stream>>>(Lre, Lim, Pre, Pim, Bre, Bim, Cre, Cim);
  s4_kernel_freq<<<NH * 4, 256, 0, stream>>>(lstep);
  s4_reorder<<<NH, 256, 0, stream>>>();
  s4_fftconv<<<NH * (NB / 2), 256, 0, stream>>>(u, y);
}

// Round 5
// 212.382 us; speedup vs baseline: 1.1697x; 1.1697x over previous
//
#include <hip/hip_runtime.h>
#include <math.h>

#define NSTATE 64
#define LEN    4096
#define NH     256
#define NB     16

// Ksym natural order (freq output); rev16-digit-reversed + (1/4096)-scaled (fftconv input)
__device__ float2 g_knat[NH * LEN];
__device__ float2 g_ksym[NH * LEN];
// per-(h,n) Cauchy params: A={lam_r,lam_i,|P|^2,pad} B={v0r,v0i,v1r,v1i} C={v2r,v2i}
__device__ float4 g_pA[NH * NSTATE];
__device__ float4 g_pB[NH * NSTATE];
__device__ float2 g_pC[NH * NSTATE];

// ---------------- complex helpers ----------------
__device__ __forceinline__ float2 cadd(float2 a, float2 b){ return make_float2(a.x+b.x, a.y+b.y); }
__device__ __forceinline__ float2 csub(float2 a, float2 b){ return make_float2(a.x-b.x, a.y-b.y); }
__device__ __forceinline__ float2 cmul(float2 a, float2 b){ return make_float2(a.x*b.x - a.y*b.y, a.x*b.y + a.y*b.x); }
__device__ __forceinline__ float2 mulnegi(float2 a){ return make_float2(a.y, -a.x); }
__device__ __forceinline__ float2 mulposi(float2 a){ return make_float2(-a.y, a.x); }

#define RSQ2 0.70710678118654752f
#define C16  0.92387953251128675613f   // cos(pi/8)
#define S16  0.38268343236508977173f   // sin(pi/8)

// 16-point DFT (W16 = e^{-2pi i/16}), natural-order in and out. 4x4 Cooley-Tukey.
__device__ __forceinline__ void bfly16_fwd(float2 v[16]) {
#pragma unroll
  for (int n1 = 0; n1 < 4; ++n1) {       // pass 1: DFT4 over stride-4 columns
    float2 a=v[n1], b=v[n1+4], c=v[n1+8], d=v[n1+12];
    float2 t0=cadd(a,c), t1=csub(a,c), t2=cadd(b,d), t3=csub(b,d);
    v[n1]    = cadd(t0,t2);
    v[n1+4]  = cadd(t1, mulnegi(t3));
    v[n1+8]  = csub(t0,t2);
    v[n1+12] = cadd(t1, mulposi(t3));
  }
  // twiddle W16^{n1*k2} on slot v[n1 + 4*k2]
  v[5]  = cmul(v[5],  make_float2(C16,-S16));                                // W1
  v[9]  = make_float2(RSQ2*(v[9].x + v[9].y),  RSQ2*(v[9].y - v[9].x));      // W2
  v[13] = cmul(v[13], make_float2(S16,-C16));                                // W3
  v[6]  = make_float2(RSQ2*(v[6].x + v[6].y),  RSQ2*(v[6].y - v[6].x));      // W2
  v[10] = mulnegi(v[10]);                                                    // W4
  v[14] = make_float2(RSQ2*(v[14].y - v[14].x), -RSQ2*(v[14].x + v[14].y));  // W6
  v[7]  = cmul(v[7],  make_float2(S16,-C16));                                // W3
  v[11] = make_float2(RSQ2*(v[11].y - v[11].x), -RSQ2*(v[11].x + v[11].y));  // W6
  v[15] = cmul(v[15], make_float2(-C16,S16));                                // W9
  float2 r[16];
#pragma unroll
  for (int k2 = 0; k2 < 4; ++k2) {       // pass 2: DFT4 over contiguous rows -> natural order
    float2 a=v[4*k2], b=v[4*k2+1], c=v[4*k2+2], d=v[4*k2+3];
    float2 t0=cadd(a,c), t1=csub(a,c), t2=cadd(b,d), t3=csub(b,d);
    r[k2]    = cadd(t0,t2);
    r[k2+4]  = cadd(t1, mulnegi(t3));
    r[k2+8]  = csub(t0,t2);
    r[k2+12] = cadd(t1, mulposi(t3));
  }
#pragma unroll
  for (int i = 0; i < 16; ++i) v[i] = r[i];
}

// conjugate-kernel (unscaled inverse) 16-point DFT
__device__ __forceinline__ void bfly16_inv(float2 v[16]) {
#pragma unroll
  for (int n1 = 0; n1 < 4; ++n1) {
    float2 a=v[n1], b=v[n1+4], c=v[n1+8], d=v[n1+12];
    float2 t0=cadd(a,c), t1=csub(a,c), t2=cadd(b,d), t3=csub(b,d);
    v[n1]    = cadd(t0,t2);
    v[n1+4]  = cadd(t1, mulposi(t3));
    v[n1+8]  = csub(t0,t2);
    v[n1+12] = cadd(t1, mulnegi(t3));
  }
  v[5]  = cmul(v[5],  make_float2(C16,S16));
  v[9]  = make_float2(RSQ2*(v[9].x - v[9].y),  RSQ2*(v[9].x + v[9].y));      // conj W2
  v[13] = cmul(v[13], make_float2(S16,C16));
  v[6]  = make_float2(RSQ2*(v[6].x - v[6].y),  RSQ2*(v[6].x + v[6].y));
  v[10] = mulposi(v[10]);
  v[14] = make_float2(-RSQ2*(v[14].x + v[14].y), RSQ2*(v[14].x - v[14].y));  // conj W6
  v[7]  = cmul(v[7],  make_float2(S16,C16));
  v[11] = make_float2(-RSQ2*(v[11].x + v[11].y), RSQ2*(v[11].x - v[11].y));
  v[15] = cmul(v[15], make_float2(-C16,-S16));
  float2 r[16];
#pragma unroll
  for (int k2 = 0; k2 < 4; ++k2) {
    float2 a=v[4*k2], b=v[4*k2+1], c=v[4*k2+2], d=v[4*k2+3];
    float2 t0=cadd(a,c), t1=csub(a,c), t2=cadd(b,d), t3=csub(b,d);
    r[k2]    = cadd(t0,t2);
    r[k2+4]  = cadd(t1, mulposi(t3));
    r[k2+8]  = csub(t0,t2);
    r[k2+12] = cadd(t1, mulnegi(t3));
  }
#pragma unroll
  for (int i = 0; i < 16; ++i) v[i] = r[i];
}

// v[m] *= w^m, m=1..15
__device__ __forceinline__ void twiddle15(float2 v[16], float wr, float wi) {
  float2 w = make_float2(wr, wi);
  float2 p = w;
  v[1] = cmul(v[1], p);
#pragma unroll
  for (int m = 2; m < 16; ++m) { p = cmul(p, w); v[m] = cmul(v[m], p); }
}

// ---------------- param precompute ----------------
__global__ __launch_bounds__(256) void s4_prep(
    const float* __restrict__ Lre, const float* __restrict__ Lim,
    const float* __restrict__ Pre, const float* __restrict__ Pim,
    const float* __restrict__ Bre, const float* __restrict__ Bim,
    const float* __restrict__ Cre, const float* __restrict__ Cim)
{
  int idx = blockIdx.x * 256 + threadIdx.x;
  if (idx >= NH * NSTATE) return;
  float lr = Lre[idx], li = Lim[idx];
  float pr = Pre[idx], pi = Pim[idx];
  float br = Bre[idx], bi = Bim[idx];
  float cr = Cre[idx], ci = Cim[idx];
  g_pA[idx] = make_float4(lr, li, pr * pr + pi * pi, 0.0f);
  g_pB[idx] = make_float4(cr * br + ci * bi, cr * bi - ci * br,
                          cr * pr + ci * pi, cr * pi - ci * pr);
  g_pC[idx] = make_float2(pr * br + pi * bi, pr * bi - pi * br);
}

// ---------------- frequency-domain S4 kernel (unchanged) ----------------
__global__ __launch_bounds__(256) void s4_kernel_freq(const float* __restrict__ log_step)
{
  const int b = blockIdx.x;
  const int h = b >> 2;
  const int q = ((b & 3) << 8) | threadIdx.x;  // 0..1023
  const float step = expf(log_step[h]);
  const float ts = 2.0f / step;
  const float NEG2PI = -6.2831853071795864769f;

  float gar, gai, car, cai, gbr, gbi, cbr, cbi;
  float gcr, gci, ccr, cci, gdr, gdi, cdr, cdi;
  {
    float so, co;
    sincosf(NEG2PI * ((float)q * (1.0f / (float)LEN)), &so, &co);
    float dr = 1.0f + co, di = so;
    float inv = 1.0f / fmaf(dr, dr, di * di);
    car = 2.0f * dr * inv; cai = -2.0f * di * inv;
    float nr = 1.0f - co, ni = -so;
    gar = ts * (fmaf(nr, dr, ni * di) * inv);
    gai = ts * (fmaf(ni, dr, -nr * di) * inv);
  }
  if (q == 0) {
    float so, co;
    sincosf(NEG2PI * 0.5f, &so, &co);
    float dr = 1.0f + co, di = so;
    float inv = 1.0f / fmaf(dr, dr, di * di);
    cbr = 2.0f * dr * inv; cbi = -2.0f * di * inv;
    float nr = 1.0f - co, ni = -so;
    gbr = ts * (fmaf(nr, dr, ni * di) * inv);
    gbi = ts * (fmaf(ni, dr, -nr * di) * inv);
  } else {
    gbr = gar; gbi = -gai; cbr = car; cbi = -cai;
  }
  {
    float so, co;
    sincosf(NEG2PI * ((float)(q + 1024) * (1.0f / (float)LEN)), &so, &co);
    float dr = 1.0f + co, di = so;
    float inv = 1.0f / fmaf(dr, dr, di * di);
    ccr = 2.0f * dr * inv; cci = -2.0f * di * inv;
    float nr = 1.0f - co, ni = -so;
    gcr = ts * (fmaf(nr, dr, ni * di) * inv);
    gci = ts * (fmaf(ni, dr, -nr * di) * inv);
  }
  gdr = gcr; gdi = -gci; cdr = ccr; cdi = -cci;

  float A00r=0,A00i=0,A01r=0,A01i=0,A10r=0,A10i=0,A11r=0,A11i=0;
  float B00r=0,B00i=0,B01r=0,B01i=0,B10r=0,B10i=0,B11r=0,B11i=0;
  float C00r=0,C00i=0,C01r=0,C01i=0,C10r=0,C10i=0,C11r=0,C11i=0;
  float D00r=0,D00i=0,D01r=0,D01i=0,D10r=0,D10i=0,D11r=0,D11i=0;

  const float4* __restrict__ pa = g_pA + h * NSTATE;
  const float4* __restrict__ pb = g_pB + h * NSTATE;
  const float2* __restrict__ pc = g_pC + h * NSTATE;

#define CAUCHY(gre, gim, k00r,k00i,k01r,k01i,k10r,k10i,k11r,k11i)            \
  {                                                                          \
    float rd = gre - Av.x, id = gim - Av.y;                                  \
    float idn = __builtin_amdgcn_rcpf(fmaf(rd, rd, id * id));                \
    float ir = rd * idn, ii = -(id * idn);                                   \
    k00r = fmaf(Bv.x, ir, k00r); k00r = fmaf(-Bv.y, ii, k00r);               \
    k00i = fmaf(Bv.x, ii, k00i); k00i = fmaf(Bv.y, ir, k00i);                \
    k01r = fmaf(Bv.z, ir, k01r); k01r = fmaf(-Bv.w, ii, k01r);               \
    k01i = fmaf(Bv.z, ii, k01i); k01i = fmaf(Bv.w, ir, k01i);                \
    k10r = fmaf(Cv.x, ir, k10r); k10r = fmaf(-Cv.y, ii, k10r);               \
    k10i = fmaf(Cv.x, ii, k10i); k10i = fmaf(Cv.y, ir, k10i);                \
    k11r = fmaf(Av.z, ir, k11r); k11i = fmaf(Av.z, ii, k11i);                \
  }

#pragma unroll 4
  for (int n = 0; n < NSTATE; ++n) {
    float4 Av = pa[n];
    float4 Bv = pb[n];
    float2 Cv = pc[n];
    CAUCHY(gar, gai, A00r,A00i,A01r,A01i,A10r,A10i,A11r,A11i)
    CAUCHY(gbr, gbi, B00r,B00i,B01r,B01i,B10r,B10i,B11r,B11i)
    CAUCHY(gcr, gci, C00r,C00i,C01r,C01i,C10r,C10i,C11r,C11i)
    CAUCHY(gdr, gdi, D00r,D00i,D01r,D01i,D10r,D10i,D11r,D11i)
  }
#undef CAUCHY

#define FINISH(cr_, ci_, k00r,k00i,k01r,k01i,k10r,k10i,k11r,k11i, Kr, Ki)    \
  {                                                                          \
    float rr = 1.0f + k11r, ri = k11i;                                       \
    float rinv = 1.0f / fmaf(rr, rr, ri * ri);                               \
    float pr_ = k01r * k10r - k01i * k10i;                                   \
    float pi_ = k01r * k10i + k01i * k10r;                                   \
    float wr = (pr_ * rr + pi_ * ri) * rinv;                                 \
    float wi = (pi_ * rr - pr_ * ri) * rinv;                                 \
    float sr = k00r - wr, si = k00i - wi;                                    \
    Kr = cr_ * sr - ci_ * si; Ki = cr_ * si + ci_ * sr;                      \
  }

  float Kar, Kai, Kbr, Kbi, Kcr, Kci, Kdr, Kdi;
  FINISH(car, cai, A00r,A00i,A01r,A01i,A10r,A10i,A11r,A11i, Kar, Kai)
  FINISH(cbr, cbi, B00r,B00i,B01r,B01i,B10r,B10i,B11r,B11i, Kbr, Kbi)
  FINISH(ccr, cci, C00r,C00i,C01r,C01i,C10r,C10i,C11r,C11i, Kcr, Kci)
  FINISH(cdr, cdi, D00r,D00i,D01r,D01i,D10r,D10i,D11r,D11i, Kdr, Kdi)
#undef FINISH

  float2* out = g_knat + (size_t)h * LEN;
  if (q == 0) {
    out[0]    = make_float2(Kar, 0.0f);
    out[2048] = make_float2(Kbr, 0.0f);
  } else {
    float fr = 0.5f * (Kar + Kbr), fi = 0.5f * (Kai - Kbi);
    out[q]        = make_float2(fr, fi);
    out[LEN - q]  = make_float2(fr, -fi);
  }
  {
    float fr = 0.5f * (Kcr + Kdr), fi = 0.5f * (Kci - Kdi);
    out[1024 + q] = make_float2(fr, fi);
    out[3072 - q] = make_float2(fr, -fi);
  }
}

// ------- reorder natural -> rev16 digit-reversed, fold in 1/4096 ifft scale -------
__global__ __launch_bounds__(256) void s4_reorder()
{
  __shared__ float2 s[LEN];   // swizzle: phys(i) = i ^ ((i>>8)&15)
  const int h = blockIdx.x, t = threadIdx.x;
  const float2* __restrict__ in = g_knat + (size_t)h * LEN;
  float2* __restrict__ out = g_ksym + (size_t)h * LEN;
  for (int i = t; i < LEN; i += 256) s[i ^ ((i >> 8) & 15)] = in[i];
  __syncthreads();
  const float sc = 1.0f / (float)LEN;
  for (int p = t; p < LEN; p += 256) {
    int f = ((p & 15) << 8) | (p & 0xF0) | (p >> 8);   // swap outer base-16 digits
    float2 k = s[f ^ ((f >> 8) & 15)];
    out[p] = make_float2(k.x * sc, k.y * sc);
  }
}

// ------------- FFT convolution: register radix-16, 4096 = 16^3 -------------
// 256 threads x 16 points. In-place stages -> 4 barriers. LDS swizzle keeps all
// patterns conflict-free. min-waves=4 (VGPR cap 128): R4's min-waves=5 capped the
// allocator at ~102 VGPRs and spilled v[]/kq[] to scratch (VGPR_Count=48,
// +220 MB scratch traffic, 106 us). Do NOT raise past 4.
#define PH(a) ((a) ^ (((a) >> 4) & 15))

__global__ __launch_bounds__(256, 4) void s4_fftconv(const float* __restrict__ u,
                                                    float* __restrict__ y)
{
  __shared__ float2 X[LEN];

  const int t = threadIdx.x;
  const int bid = blockIdx.x;
  const int h  = bid & (NH - 1);
  const int bp = bid >> 8;          // packs batches (bp, bp+8) as re/im

  float cA, sA, cB, sB;
  sincosf((float)t        * (-6.2831853071795864769f / 4096.0f), &sA, &cA);
  sincosf((float)(t & 15) * (-6.2831853071795864769f /  256.0f), &sB, &cB);

  const float* u1 = u + ((size_t)bp * NH + h) * LEN;
  const float* u2 = u + ((size_t)(bp + 8) * NH + h) * LEN;

  float2 v[16];
  // ---- fwd stage A (sets {j + 256 m}, j = t): global -> regs, coalesced
#pragma unroll
  for (int m = 0; m < 16; ++m)
    v[m] = make_float2(u1[t + 256 * m], u2[t + 256 * m]);
  bfly16_fwd(v);
  twiddle15(v, cA, sA);
#pragma unroll
  for (int m = 0; m < 16; ++m) { int a = t + 256 * m; X[PH(a)] = v[m]; }
  __syncthreads();

  // ---- fwd stage B (sets {Bk*256 + j2 + 16 s}), in-place
  const int baseB = (t >> 4) * 256 + (t & 15);
#pragma unroll
  for (int s = 0; s < 16; ++s) { int a = baseB + 16 * s; v[s] = X[PH(a)]; }
  bfly16_fwd(v);
  twiddle15(v, cB, sB);
#pragma unroll
  for (int n = 0; n < 16; ++n) { int a = baseB + 16 * n; X[PH(a)] = v[n]; }
  __syncthreads();

  // ---- fused middle: fwd stage C + pointwise K (rev16 order, pre-scaled) + inv C'
  {
    const float4* kp = (const float4*)(g_ksym + (size_t)h * LEN + 16 * t);
    float4 ka[4];
#pragma unroll
    for (int i = 0; i < 4; ++i) ka[i] = kp[i];   // first half early: overlaps LDS reads
#pragma unroll
    for (int k = 0; k < 16; ++k) { int a = 16 * t + k; v[k] = X[PH(a)]; }
    float4 kb[4];
#pragma unroll
    for (int i = 0; i < 4; ++i) kb[i] = kp[4 + i]; // second half: overlaps fwd butterfly
    bfly16_fwd(v);
#pragma unroll
    for (int i = 0; i < 4; ++i) {
      v[2*i]   = cmul(v[2*i],   make_float2(ka[i].x, ka[i].y));
      v[2*i+1] = cmul(v[2*i+1], make_float2(ka[i].z, ka[i].w));
    }
#pragma unroll
    for (int i = 0; i < 4; ++i) {
      v[8+2*i]   = cmul(v[8+2*i],   make_float2(kb[i].x, kb[i].y));
      v[8+2*i+1] = cmul(v[8+2*i+1], make_float2(kb[i].z, kb[i].w));
    }
    bfly16_inv(v);
#pragma unroll
    for (int k = 0; k < 16; ++k) { int a = 16 * t + k; X[PH(a)] = v[k]; }
  }
  __syncthreads();

  // ---- inv stage B' : conj twiddle BEFORE inverse butterfly, in-place
#pragma unroll
  for (int n = 0; n < 16; ++n) { int a = baseB + 16 * n; v[n] = X[PH(a)]; }
  twiddle15(v, cB, -sB);
  bfly16_inv(v);
#pragma unroll
  for (int s = 0; s < 16; ++s) { int a = baseB + 16 * s; X[PH(a)] = v[s]; }
  __syncthreads();

  // ---- inv stage A' : output natural order, straight to global
#pragma unroll
  for (int m = 0; m < 16; ++m) { int a = t + 256 * m; v[m] = X[PH(a)]; }
  twiddle15(v, cA, -sA);
  bfly16_inv(v);

  float* y1 = y + ((size_t)bp * NH + h) * LEN;
  float* y2 = y + ((size_t)(bp + 8) * NH + h) * LEN;
#pragma unroll
  for (int s = 0; s < 16; ++s) {
    y1[t + 256 * s] = v[s].x;     // batch bp   = Re (1/4096 folded into K)
    y2[t + 256 * s] = v[s].y;     // batch bp+8 = Im
  }
}

extern "C" void kernel_launch(void* const* d_in, const int* in_sizes, int n_in,
                              void* d_out, int out_size, void* d_ws, size_t ws_size,
                              hipStream_t stream) {
  const float* u    = (const float*)d_in[0];
  const float* Lre  = (const float*)d_in[1];
  const float* Lim  = (const float*)d_in[2];
  const float* Pre  = (const float*)d_in[3];
  const float* Pim  = (const float*)d_in[4];
  const float* Bre  = (const float*)d_in[5];
  const float* Bim  = (const float*)d_in[6];
  const float* Cre  = (const float*)d_in[7];
  const float* Cim  = (const float*)d_in[8];
  const float* lstep = (const float*)d_in[9];
  float* y = (float*)d_out;

  s4_prep<<<(NH * NSTATE + 255) / 256, 256, 0, stream>>>(Lre, Lim, Pre, Pim, Bre, Bim, Cre, Cim);
  s4_kernel_freq<<<NH * 4, 256, 0, stream>>>(lstep);
  s4_reorder<<<NH, 256, 0, stream>>>();
  s4_fftconv<<<NH * (NB / 2), 256, 0, stream>>>(u, y);
}